// Round 13
// baseline (244.094 us; speedup 1.0000x reference)
//
#include <hip/hip_runtime.h>
#include <hip/hip_bf16.h>
#include <math.h>

#define B_    4
#define N_    4096
#define DIM_  256
#define H_    8
#define DH_   64
#define P_    2
#define INNER_ 512
#define BN_   (B_ * N_)      // 16384 rows for q/out
#define KVR_  (2 * BN_)      // 32768 rows for k/v

typedef short v8s  __attribute__((ext_vector_type(8)));
typedef short v4s  __attribute__((ext_vector_type(4)));
typedef float v4f  __attribute__((ext_vector_type(4)));

__device__ __forceinline__ short f2b(float x) {
    __hip_bfloat16 h = __float2bfloat16(x);
    return *reinterpret_cast<short*>(&h);
}
__device__ __forceinline__ float b2f(short s) {
    __hip_bfloat16 h = *reinterpret_cast<__hip_bfloat16*>(&s);
    return __bfloat162float(h);
}

__device__ __forceinline__ void async16(const void* g, void* l) {
    __builtin_amdgcn_global_load_lds(
        (const __attribute__((address_space(1))) void*)g,
        (__attribute__((address_space(3))) void*)l, 16, 0, 0);
}

// 16 consecutive elements of one row -> wide stores
__device__ __forceinline__ void storeRow(float* p, float4 f0, float4 f1, float4 f2, float4 f3) {
    ((float4*)p)[0] = f0; ((float4*)p)[1] = f1; ((float4*)p)[2] = f2; ((float4*)p)[3] = f3;
}
__device__ __forceinline__ void storeRow(__hip_bfloat16* p, float4 f0, float4 f1, float4 f2, float4 f3) {
    v8s o0, o1;
    o0[0]=f2b(f0.x); o0[1]=f2b(f0.y); o0[2]=f2b(f0.z); o0[3]=f2b(f0.w);
    o0[4]=f2b(f1.x); o0[5]=f2b(f1.y); o0[6]=f2b(f1.z); o0[7]=f2b(f1.w);
    o1[0]=f2b(f2.x); o1[1]=f2b(f2.y); o1[2]=f2b(f2.z); o1[3]=f2b(f2.w);
    o1[4]=f2b(f3.x); o1[5]=f2b(f3.y); o1[6]=f2b(f3.z); o1[7]=f2b(f3.w);
    ((v8s*)p)[0] = o0; ((v8s*)p)[1] = o1;
}

// ---------------------------------------------------------------------------
// MERGED weight prep, one dispatch (see R9 comments).
// ---------------------------------------------------------------------------
__global__ __launch_bounds__(256) void prep_all(
    const float* __restrict__ Wq, const float* __restrict__ gq, const float* __restrict__ betaq,
    const float* __restrict__ Wk, const float* __restrict__ gk, const float* __restrict__ betak,
    const float* __restrict__ bk,
    const float* __restrict__ Wv, const float* __restrict__ gv, const float* __restrict__ betav,
    const float* __restrict__ bv,
    const float* __restrict__ Woff, const float* __restrict__ Wout,
    short* __restrict__ Wq2t, float* __restrict__ bq2,
    short* __restrict__ Wkvt, float* __restrict__ bkv,
    float* __restrict__ Wcomb, float* __restrict__ braw, short* __restrict__ Woutb) {
    __shared__ float sm[272];
    const int bid = blockIdx.x, t = threadIdx.x;

    if (bid < 1536) {
        const float *W, *g, *beta, *bias_in;
        short* Wt; float* b2; int K, n; float scale;
        if (bid < 512)       { W=Wq; g=gq; beta=betaq; bias_in=nullptr; Wt=Wq2t; b2=bq2; K=512; n=bid;        scale=0.125f; }
        else if (bid < 1024) { W=Wk; g=gk; beta=betak; bias_in=bk; Wt=Wkvt;           b2=bkv;       K=256; n=bid-512;  scale=1.f; }
        else                 { W=Wv; g=gv; beta=betav; bias_in=bv; Wt=Wkvt+512*256;   b2=bkv+512;   K=256; n=bid-1024; scale=1.f; }
        float partial = 0.f;
        for (int k = t; k < K; k += 256) {
            float w = W[k * 512 + n];
            Wt[(size_t)n * K + k] = f2b(scale * g[k] * w);
            partial += beta[k] * w;
        }
        sm[t] = partial;
        __syncthreads();
        for (int s = 128; s > 0; s >>= 1) {
            if (t < s) sm[t] += sm[t + s];
            __syncthreads();
        }
        if (t == 0) b2[n] = scale * ((bias_in ? bias_in[n] : 0.f) + sm[0]);
    } else if (bid < 2048) {
        const int k = bid - 1536;
        const int hp = t & 15, jg = t >> 4;
        float p = 0.f;
        for (int j = jg; j < INNER_; j += 16)
            p += Wq[k * INNER_ + j] * Woff[hp * INNER_ + j];
        sm[jg * 17 + hp] = p;
        __syncthreads();
        if (t < 16) {
            float s = 0.f;
            for (int i = 0; i < 16; i++) s += sm[i * 17 + t];
            Wcomb[k * 16 + t] = gq[k] * s;
            braw[k * 16 + t]  = betaq[k] * s;
        }
    } else {
        const int i0 = (bid - 2048) * 1024 + t * 4;
        float4 f = *(const float4*)(Wout + i0);
        v4s o;
        o[0] = f2b(f.x); o[1] = f2b(f.y); o[2] = f2b(f.z); o[3] = f2b(f.w);
        *(v4s*)(Woutb + i0) = o;
    }
}

// bcomb[hp] = sum_k braw[k][hp] + boff[hp]  (deterministic 1-block reduce)
__global__ void bcomb_sum(const float* __restrict__ braw, const float* __restrict__ boff,
                          float* __restrict__ bcomb) {
    __shared__ float sm[272];
    int t = threadIdx.x;
    int hp = t & 15, kg = t >> 4;
    float p = 0.f;
    for (int k = kg; k < 512; k += 16) p += braw[k * 16 + hp];
    sm[kg * 17 + hp] = p;
    __syncthreads();
    if (t < 16) {
        float s = 0.f;
        for (int i = 0; i < 16; i++) s += sm[i * 17 + t];
        bcomb[t] = s + boff[t];
    }
}

// ---------------------------------------------------------------------------
// FUSED single-pass LN + activations + offsets. One wave per 4 rows.
// ---------------------------------------------------------------------------
__global__ __launch_bounds__(256) void norm_fused_kernel(
    const float* __restrict__ x, const float* __restrict__ p,
    const float* __restrict__ Wcomb, const float* __restrict__ bcomb,
    short* __restrict__ Aq, short* __restrict__ Akv,
    float* __restrict__ out_off, int* __restrict__ idx) {
    const int lane = threadIdx.x & 63;
    const int wv   = threadIdx.x >> 6;
    const int m0   = (blockIdx.x * 4 + wv) * 4;   // first of 4 rows
    const int k8   = lane * 8;

    float4 w[8][4];
#pragma unroll
    for (int i = 0; i < 8; i++) {
        const float4* wr = (const float4*)(Wcomb + (size_t)(k8 + i) * 16);
#pragma unroll
        for (int j = 0; j < 4; j++) w[i][j] = wr[j];
    }
    const float bc = bcomb[lane & 15];

    const float* srcb = (lane < 32) ? (x + k8) : (p + k8 - DIM_);

    float4 u0 = ((const float4*)(srcb + (size_t)m0 * DIM_))[0];
    float4 u1 = ((const float4*)(srcb + (size_t)m0 * DIM_))[1];

#pragma unroll
    for (int r = 0; r < 4; r++) {
        const int m = m0 + r;
        float4 n0, n1;
        if (r < 3) {
            n0 = ((const float4*)(srcb + (size_t)(m + 1) * DIM_))[0];
            n1 = ((const float4*)(srcb + (size_t)(m + 1) * DIM_))[1];
        }
        float uv[8] = { u0.x, u0.y, u0.z, u0.w, u1.x, u1.y, u1.z, u1.w };

        float s = 0.f, q2 = 0.f;
#pragma unroll
        for (int i = 0; i < 8; i++) { s += uv[i]; q2 += uv[i] * uv[i]; }
#pragma unroll
        for (int d = 1; d <= 16; d <<= 1) {
            s  += __shfl_xor(s, d);
            q2 += __shfl_xor(q2, d);
        }
        float mean_h = s * (1.f / 256.f);
        float var_h  = q2 * (1.f / 256.f) - mean_h * mean_h;
        float rstd_h = rsqrtf(var_h + 1e-5f);
        float sf  = s  + __shfl_xor(s, 32);
        float q2f = q2 + __shfl_xor(q2, 32);
        float mean_q = sf * (1.f / 512.f);
        float var_q  = q2f * (1.f / 512.f) - mean_q * mean_q;
        float rstd_q = rsqrtf(var_q + 1e-5f);

        v8s okv;
#pragma unroll
        for (int i = 0; i < 8; i++) okv[i] = f2b((uv[i] - mean_h) * rstd_h);
        short* akvdst = Akv + ((lane < 32) ? ((size_t)m * DIM_ + k8)
                                           : ((size_t)(BN_ + m) * DIM_ + k8 - DIM_));
        *(v8s*)akvdst = okv;

        float nv[8];
        v8s oq;
#pragma unroll
        for (int i = 0; i < 8; i++) { nv[i] = (uv[i] - mean_q) * rstd_q; oq[i] = f2b(nv[i]); }
        *(v8s*)(Aq + (size_t)m * INNER_ + k8) = oq;

        float acc[16];
#pragma unroll
        for (int h = 0; h < 16; h++) acc[h] = 0.f;
#pragma unroll
        for (int i = 0; i < 8; i++) {
            float nvi = nv[i];
            acc[0]  += nvi * w[i][0].x;  acc[1]  += nvi * w[i][0].y;
            acc[2]  += nvi * w[i][0].z;  acc[3]  += nvi * w[i][0].w;
            acc[4]  += nvi * w[i][1].x;  acc[5]  += nvi * w[i][1].y;
            acc[6]  += nvi * w[i][1].z;  acc[7]  += nvi * w[i][1].w;
            acc[8]  += nvi * w[i][2].x;  acc[9]  += nvi * w[i][2].y;
            acc[10] += nvi * w[i][2].z;  acc[11] += nvi * w[i][2].w;
            acc[12] += nvi * w[i][3].x;  acc[13] += nvi * w[i][3].y;
            acc[14] += nvi * w[i][3].z;  acc[15] += nvi * w[i][3].w;
        }
        float a8[8];
#pragma unroll
        for (int j = 0; j < 8; j++) {
            float lo = acc[2 * j] + __shfl_xor(acc[2 * j], 1);
            float hi = acc[2 * j + 1] + __shfl_xor(acc[2 * j + 1], 1);
            a8[j] = (lane & 1) ? hi : lo;
        }
        float a4[4];
#pragma unroll
        for (int j = 0; j < 4; j++) {
            float lo = a8[2 * j] + __shfl_xor(a8[2 * j], 2);
            float hi = a8[2 * j + 1] + __shfl_xor(a8[2 * j + 1], 2);
            a4[j] = (lane & 2) ? hi : lo;
        }
        float a2[2];
#pragma unroll
        for (int j = 0; j < 2; j++) {
            float lo = a4[2 * j] + __shfl_xor(a4[2 * j], 4);
            float hi = a4[2 * j + 1] + __shfl_xor(a4[2 * j + 1], 4);
            a2[j] = (lane & 4) ? hi : lo;
        }
        float l1 = a2[0] + __shfl_xor(a2[0], 8);
        float h1 = a2[1] + __shfl_xor(a2[1], 8);
        float a1 = (lane & 8) ? h1 : l1;
        a1 += __shfl_xor(a1, 16);
        a1 += __shfl_xor(a1, 32);

        if (lane < 16) {
            float off = a1 + bc;
            int b = m >> 12, n = m & (N_ - 1);
            int h = lane >> 1, pp = lane & 1;
            out_off[(size_t)((b * H_ + h) * P_ + pp) * N_ + n] = off;
            float f = fminf(fmaxf((float)n + off, 0.f), (float)(2 * N_ - 1));
            idx[((size_t)(b * H_ + h) * N_ + n) * P_ + pp] = (int)f;
        }
        u0 = n0; u1 = n1;
    }
}

// ---------------------------------------------------------------------------
// bf16 MFMA GEMM body v2 (fixed): C[.][N] = A[.][K] @ Bt[N][K]^T + bias.
// 128x128 tile, 4 waves (2x2), 4x4 frags of 16x16x32 / wave. N,K,NX constant.
//  - XCD swizzle (panel pinned to one XCD).
//  - A-ONLY LDS staging, DOUBLE-BUFFERED (16KB x2), 4 chunks/thread
//    (1024 chunks = full 128x64 tile; R12 staged only half -> NaN).
//    DMA for tile i+1 issued right after iter i's barrier -> the vmcnt
//    drain at the NEXT barrier waits on loads a full MFMA phase old.
//  - B fragments loaded DIRECTLY from global (weights L2-resident):
//    halves LDS staging and fragment ds_read traffic.
//  - XOR chunk swizzle on A: fragment ds_read_b128 conflict-free.
//  - Epilogue: per-wave LDS transpose, intra-wave sync only.
// ---------------------------------------------------------------------------
template <typename OT, int N, int K, int NX>
__device__ __forceinline__ void gemm_body(
    short* smem, const short* __restrict__ A, const short* __restrict__ Bt,
    const float* __restrict__ bias, OT* __restrict__ C, int lin) {
    const int tid  = threadIdx.x;
    const int lane = tid & 63, w = tid >> 6;
    const int wr = w >> 1, wc = w & 1;
    const int lm = lane & 15, g = lane >> 4;

    const int x8 = lin & 7, t = lin >> 3;
    const int bx = t % NX, by = (t / NX) * 8 + x8;
    const int row0 = by * 128, col0 = bx * 128;

    // A staging: 1024 chunks of 16B per buffer; 4 chunks per thread
    const short* pa[4];
    int ss[4];
#pragma unroll
    for (int r = 0; r < 4; r++) {
        int s   = tid + 256 * r;
        int row = s >> 3, kcs = s & 7;
        int kg  = kcs ^ (row & 7);
        ss[r] = s;
        pa[r] = A + (size_t)(row0 + row) * K + kg * 8;
    }

    // B fragment base: row (col0 + wc*64 + j*16 + lm), k-offset g*8
    const short* pB = Bt + (size_t)(col0 + wc * 64 + lm) * K + g * 8;

    v4f acc[4][4];
#pragma unroll
    for (int i = 0; i < 4; i++)
#pragma unroll
        for (int j = 0; j < 4; j++) acc[i][j] = (v4f){0.f, 0.f, 0.f, 0.f};

    // prologue: DMA tile 0 -> buffer 0
#pragma unroll
    for (int r = 0; r < 4; r++)
        async16(pa[r], (char*)smem + ss[r] * 16);

    constexpr int NI = K / 64;
#pragma unroll
    for (int it = 0; it < NI; it++) {
        short* As = smem + (it & 1) * 8192;
        __syncthreads();   // drains DMA(it) (in flight since last iter); other buf free
        if (it + 1 < NI) {
            short* Asn = smem + ((it + 1) & 1) * 8192;
#pragma unroll
            for (int r = 0; r < 4; r++)
                async16(pa[r] + (it + 1) * 64, (char*)Asn + ss[r] * 16);
        }
        const int k0 = it * 64;
#pragma unroll
        for (int ks = 0; ks < 2; ks++) {
            v8s af[4], bf[4];
#pragma unroll
            for (int i = 0; i < 4; i++) {
                int m   = wr * 64 + i * 16 + lm;
                int sch = m * 8 + ((ks * 4 + g) ^ (m & 7));
                af[i] = *(const v8s*)(As + sch * 8);
            }
#pragma unroll
            for (int j = 0; j < 4; j++)
                bf[j] = *(const v8s*)(pB + (size_t)(j * 16) * K + k0 + ks * 32);
#pragma unroll
            for (int i = 0; i < 4; i++)
#pragma unroll
                for (int j = 0; j < 4; j++)
                    acc[i][j] = __builtin_amdgcn_mfma_f32_16x16x32_bf16(af[i], bf[j], acc[i][j], 0, 0, 0);
        }
    }

#pragma unroll
    for (int j = 0; j < 4; j++) {
        int gc = col0 + wc * 64 + j * 16 + lm;
        float bj = bias ? bias[gc] : 0.f;
#pragma unroll
        for (int i = 0; i < 4; i++)
#pragma unroll
            for (int r = 0; r < 4; r++) acc[i][j][r] += bj;
    }

    // epilogue: per-wave 16x64 transpose; intra-wave sync only
    __syncthreads();   // all waves done with staging buffers (ep aliases them)
    float* ep = (float*)smem + w * (16 * 68);
#pragma unroll
    for (int i = 0; i < 4; i++) {
#pragma unroll
        for (int j = 0; j < 4; j++)
#pragma unroll
            for (int r = 0; r < 4; r++)
                ep[(g * 4 + r) * 68 + j * 16 + lm] = acc[i][j][r];
        asm volatile("s_waitcnt lgkmcnt(0)" ::: "memory");  // writes visible (lockstep wave)
        int rr = lane >> 2, cb = (lane & 3) * 16;
        float4 f0 = *(float4*)(ep + rr * 68 + cb + 0);
        float4 f1 = *(float4*)(ep + rr * 68 + cb + 4);
        float4 f2 = *(float4*)(ep + rr * 68 + cb + 8);
        float4 f3 = *(float4*)(ep + rr * 68 + cb + 12);
        asm volatile("s_waitcnt lgkmcnt(0)" ::: "memory");  // reads landed before next i's writes
        int grow = row0 + wr * 64 + i * 16 + rr;
        int gcol = col0 + wc * 64 + cb;
        storeRow(&C[(size_t)grow * N + gcol], f0, f1, f2, f3);
    }
}

// merged q + kv projection GEMMs (independent; block-range dispatch)
__global__ __launch_bounds__(256) void gemm_qkv(
    const short* __restrict__ Aq, const short* __restrict__ Wq2t,
    const float* __restrict__ bq2, __hip_bfloat16* __restrict__ qb,
    const short* __restrict__ Akv, const short* __restrict__ Wkvt,
    const float* __restrict__ bkv, __hip_bfloat16* __restrict__ kvproj) {
    __shared__ short smem[2 * 128 * 64];
    const int bid = blockIdx.x;
    if (bid < 512)
        gemm_body<__hip_bfloat16, 512, 512, 4>(smem, Aq, Wq2t, bq2, qb, bid);
    else
        gemm_body<__hip_bfloat16, 1024, 256, 8>(smem, Akv, Wkvt, bkv, kvproj, bid - 512);
}

// output projection GEMM
__global__ __launch_bounds__(256) void gemm_out(
    const short* __restrict__ A, const short* __restrict__ Bt,
    const float* __restrict__ bias, float* __restrict__ C) {
    __shared__ short smem[2 * 128 * 64];
    const int lin = blockIdx.y * gridDim.x + blockIdx.x;
    gemm_body<float, 256, 512, 2>(smem, A, Bt, bias, C, lin);
}

// ---------------------------------------------------------------------------
// Attention: 16-lane groups, 4 samples/wave. Lane owns 4-elem DH slice.
// kvproj layout [row][1024]: k cols 0-511, v 512+. q pre-scaled by 0.125.
// ---------------------------------------------------------------------------
__global__ __launch_bounds__(256) void attn_kernel(
    const short* __restrict__ qb, const short* __restrict__ kvproj,
    const int* __restrict__ idx, short* __restrict__ attnout) {
    const int lane = threadIdx.x & 63;
    const int wv   = threadIdx.x >> 6;
    const int s    = lane >> 4, c = lane & 15;
    const int n = blockIdx.x * 16 + wv * 4 + s;
    const int h = blockIdx.y, b = blockIdx.z;
    const int m = b * N_ + n;

    v4s qv = *(const v4s*)(qb + (size_t)m * INNER_ + h * DH_ + c * 4);

    const int* ip = idx + ((size_t)(b * H_ + h) * N_ + n) * P_;
    int j0 = ip[0], j1 = ip[1];
    int r0 = b * N_ + j0 + ((j0 >= N_) ? (BN_ - N_) : 0);
    int r1 = b * N_ + j1 + ((j1 >= N_) ? (BN_ - N_) : 0);
    const short* k0p = kvproj + (size_t)r0 * 1024 + h * DH_ + c * 4;
    const short* k1p = kvproj + (size_t)r1 * 1024 + h * DH_ + c * 4;
    v4s k0 = *(const v4s*)k0p, v0 = *(const v4s*)(k0p + 512);
    v4s k1 = *(const v4s*)k1p, v1 = *(const v4s*)(k1p + 512);

    float q0 = b2f(qv[0]), q1 = b2f(qv[1]), q2 = b2f(qv[2]), q3 = b2f(qv[3]);
    float s0 = q0 * b2f(k0[0]) + q1 * b2f(k0[1]) + q2 * b2f(k0[2]) + q3 * b2f(k0[3]);
    float s1 = q0 * b2f(k1[0]) + q1 * b2f(k1[1]) + q2 * b2f(k1[2]) + q3 * b2f(k1[3]);
#pragma unroll
    for (int d = 1; d <= 8; d <<= 1) {
        s0 += __shfl_xor(s0, d);
        s1 += __shfl_xor(s1, d);
    }
    float mx = fmaxf(s0, s1);
    float e0 = __expf(s0 - mx), e1 = __expf(s1 - mx);
    float inv = 1.f / (e0 + e1);
    v4s o;
#pragma unroll
    for (int i = 0; i < 4; i++)
        o[i] = f2b((e0 * b2f(v0[i]) + e1 * b2f(v1[i])) * inv);
    *(v4s*)(attnout + (size_t)m * INNER_ + h * DH_ + c * 4) = o;
}

// ---------------------------------------------------------------------------
extern "C" void kernel_launch(void* const* d_in, const int* in_sizes, int n_in,
                              void* d_out, int out_size, void* d_ws, size_t ws_size,
                              hipStream_t stream) {
    (void)in_sizes; (void)n_in; (void)out_size; (void)ws_size;

    const float* x      = (const float*)d_in[0];
    const float* prevx  = (const float*)d_in[1];
    const float* ln_q_g = (const float*)d_in[2];
    const float* ln_q_b = (const float*)d_in[3];
    const float* ln_k_g = (const float*)d_in[4];
    const float* ln_k_b = (const float*)d_in[5];
    const float* ln_v_g = (const float*)d_in[6];
    const float* ln_v_b = (const float*)d_in[7];
    const float* Wq     = (const float*)d_in[8];
    const float* Wk     = (const float*)d_in[9];
    const float* bk     = (const float*)d_in[10];
    const float* Wv     = (const float*)d_in[11];
    const float* bv     = (const float*)d_in[12];
    const float* Woff   = (const float*)d_in[13];
    const float* boff   = (const float*)d_in[14];
    const float* Wout   = (const float*)d_in[15];
    const float* bout   = (const float*)d_in[16];

    char* cur = (char*)d_ws;
    auto alloc = [&](size_t bytes) { char* p = cur; cur += (bytes + 255) & ~(size_t)255; return p; };
    short* Aq      = (short*)alloc((size_t)BN_ * INNER_ * 2);     // 16 MB
    short* Akv     = (short*)alloc((size_t)KVR_ * DIM_ * 2);      // 16 MB
    short* qb      = (short*)alloc((size_t)BN_ * INNER_ * 2);     // 16 MB
    short* kvproj  = (short*)alloc((size_t)KVR_ * 1024 * 2);      // 64 MB
    short* attnout = (short*)alloc((size_t)BN_ * INNER_ * 2);     // 16 MB
    short* Wq2t    = (short*)alloc(512 * 512 * 2);
    short* Wkvt    = (short*)alloc(1024 * 256 * 2);
    short* Woutb   = (short*)alloc(256 * 512 * 2);
    float* bq2     = (float*)alloc(512 * 4);
    float* bkv     = (float*)alloc(1024 * 4);
    float* Wcomb   = (float*)alloc(512 * 16 * 4);
    float* braw    = (float*)alloc(512 * 16 * 4);
    float* bcomb   = (float*)alloc(16 * 4);
    int*   idxb    = (int*)alloc((size_t)BN_ * 16 * 4);
    // total ~130 MB

    float* out_main = (float*)d_out;                      // (B,N,DIM)
    float* out_off  = out_main + (size_t)BN_ * DIM_;      // (B,H,P,N)

    // 1) merged weight prep + composed offset weights
    prep_all<<<2176, 256, 0, stream>>>(Wq, ln_q_g, ln_q_b,
                                       Wk, ln_k_g, ln_k_b, bk,
                                       Wv, ln_v_g, ln_v_b, bv,
                                       Woff, Wout,
                                       Wq2t, bq2, Wkvt, bkv, Wcomb, braw, Woutb);
    bcomb_sum<<<1, 256, 0, stream>>>(braw, boff, bcomb);

    // 2) single-pass fused LN + activations + offsets + indices (4 rows/wave)
    norm_fused_kernel<<<BN_ / 16, 256, 0, stream>>>(x, prevx, Wcomb, bcomb,
                                                    Aq, Akv, out_off, idxb);

    // 3) q + kv projections, one dispatch
    gemm_qkv<<<2560, 256, 0, stream>>>(Aq, Wq2t, bq2, (__hip_bfloat16*)qb,
                                       Akv, Wkvt, bkv, (__hip_bfloat16*)kvproj);

    // 4) gather + softmax(P=2) + weighted sum (16-lane groups, 4 samples/wave)
    dim3 ga(N_ / 16, H_, B_);
    attn_kernel<<<ga, 256, 0, stream>>>(qb, kvproj, idxb, attnout);

    // 5) output projection
    gemm_out<<<dim3(2, 128), 256, 0, stream>>>(attnout, Woutb, bout, out_main);
}